// Round 3
// baseline (124.674 us; speedup 1.0000x reference)
//
#include <hip/hip_runtime.h>

// 16-step spike recurrence, elementwise.
// z_t = (v_t > T_t) since (v-T)/(|v|+1) > 0 <=> v > T (denominator >= 1).
// R3: R2's unroll-by-4 grid-stride with the H-index bug fixed:
// step t computes v -= z_{t-1} * H[t]  (H index == current step).

__device__ __constant__ const float kH[16] = {
    -0.73437643f, 3.319645f,   2.1290164f,  3.6901689f,
    3.302721f,    3.2154958f,  2.9151256f,  3.1718695f,
    3.1084518f,   2.6179547f,  2.235003f,   1.2864777f,
    0.52327204f, -0.08344932f, -1.8249638f, 3.0859442f};

__device__ __constant__ const float kD[16] = {
    3.3848417f, -0.07072583f, 3.691287f,   3.3074934f,
    3.2120926f,  2.9196491f,  3.1727686f,  3.1054153f,
    2.621943f,   2.2355895f,  1.2878408f,  0.52468026f,
    0.12632068f, 0.14482783f, 0.3153498f,  0.13054803f};

__device__ __constant__ const float kT[16] = {
    3.1538513f, -1.0211663f,  1.3714716f,  1.0718397f,
    1.0049332f,  0.68078244f, 1.0151638f,  0.8858697f,
    0.4037103f,  0.01490025f, -0.90781677f, -1.6859558f,
    -1.9241625f, -2.0441303f, 0.279356f,   0.1315174f};

__device__ __forceinline__ float spike_chain(float v) {
    // Step 0 peeled: z_{-1}=0 so v unchanged (H[0] multiplied by 0);
    // out = (v>T0) ? D0 : 0.
    float z = (v > kT[0]) ? 1.0f : 0.0f;
    float out = z * kD[0];
#pragma unroll
    for (int t = 1; t < 16; ++t) {
        v = fmaf(-z, kH[t], v);          // v -= z_{t-1} * H[t]  (z in {0,1})
        z = (v > kT[t]) ? 1.0f : 0.0f;   // spike
        out = fmaf(z, kD[t], out);       // out += z*D[t]
    }
    return out;
}

__device__ __forceinline__ float4 spike4(float4 v) {
    float4 o;
    o.x = spike_chain(v.x);
    o.y = spike_chain(v.y);
    o.z = spike_chain(v.z);
    o.w = spike_chain(v.w);
    return o;
}

__global__ __launch_bounds__(256) void spike_kernel(const float4* __restrict__ x,
                                                    float4* __restrict__ out,
                                                    int n4) {
    const int tid = blockIdx.x * blockDim.x + threadIdx.x;
    const int T = gridDim.x * blockDim.x;   // total threads
    const int chunk = 4 * T;

    int i = tid;
    // Main unrolled-by-4 loop: 4 independent float4 loads in flight.
    for (; i + 3 * T < n4; i += chunk) {
        float4 a = x[i];
        float4 b = x[i + T];
        float4 c = x[i + 2 * T];
        float4 d = x[i + 3 * T];
        float4 ra = spike4(a);
        float4 rb = spike4(b);
        float4 rc = spike4(c);
        float4 rd = spike4(d);
        out[i] = ra;
        out[i + T] = rb;
        out[i + 2 * T] = rc;
        out[i + 3 * T] = rd;
    }
    // Tail (not taken for the bench shape: n4 = 16,777,216 divides evenly).
    for (; i < n4; i += T) {
        out[i] = spike4(x[i]);
    }
}

extern "C" void kernel_launch(void* const* d_in, const int* in_sizes, int n_in,
                              void* d_out, int out_size, void* d_ws, size_t ws_size,
                              hipStream_t stream) {
    const float* x = (const float*)d_in[0];
    float* out = (float*)d_out;
    int n = in_sizes[0];          // 16*4096*1024 = 67,108,864 (divisible by 4)
    int n4 = n >> 2;

    const int block = 256;
    int grid = (n4 + block - 1) / block;
    if (grid > 2048) grid = 2048;  // 8 blocks/CU on 256 CUs

    spike_kernel<<<grid, block, 0, stream>>>(
        (const float4*)x, (float4*)out, n4);
}

// Round 5
// 97.500 us; speedup vs baseline: 1.2787x; 1.2787x over previous
//
#include <hip/hip_runtime.h>

// 16-step spike recurrence, elementwise.
// z_t = (v_t > T_t) since (v-T)/(|v|+1) > 0 <=> v > T (denominator >= 1).
// R5: R4 with native clang vector type (ext_vector_type) so
// __builtin_nontemporal_store compiles. Nontemporal stores keep the
// 256 MiB L3 entirely for x (exactly 256 MiB); exact-cover grid.

typedef float f32x4 __attribute__((ext_vector_type(4)));

__device__ __constant__ const float kH[16] = {
    -0.73437643f, 3.319645f,   2.1290164f,  3.6901689f,
    3.302721f,    3.2154958f,  2.9151256f,  3.1718695f,
    3.1084518f,   2.6179547f,  2.235003f,   1.2864777f,
    0.52327204f, -0.08344932f, -1.8249638f, 3.0859442f};

__device__ __constant__ const float kD[16] = {
    3.3848417f, -0.07072583f, 3.691287f,   3.3074934f,
    3.2120926f,  2.9196491f,  3.1727686f,  3.1054153f,
    2.621943f,   2.2355895f,  1.2878408f,  0.52468026f,
    0.12632068f, 0.14482783f, 0.3153498f,  0.13054803f};

__device__ __constant__ const float kT[16] = {
    3.1538513f, -1.0211663f,  1.3714716f,  1.0718397f,
    1.0049332f,  0.68078244f, 1.0151638f,  0.8858697f,
    0.4037103f,  0.01490025f, -0.90781677f, -1.6859558f,
    -1.9241625f, -2.0441303f, 0.279356f,   0.1315174f};

__device__ __forceinline__ float spike_chain(float v) {
    // Step 0 peeled: z_{-1}=0 so v unchanged; out = (v>T0) ? D0 : 0.
    float z = (v > kT[0]) ? 1.0f : 0.0f;
    float out = z * kD[0];
#pragma unroll
    for (int t = 1; t < 16; ++t) {
        v = fmaf(-z, kH[t], v);          // v -= z_{t-1} * H[t]  (z in {0,1})
        z = (v > kT[t]) ? 1.0f : 0.0f;   // spike
        out = fmaf(z, kD[t], out);       // out += z*D[t]
    }
    return out;
}

__device__ __forceinline__ f32x4 spike4(f32x4 v) {
    f32x4 o;
    o.x = spike_chain(v.x);
    o.y = spike_chain(v.y);
    o.z = spike_chain(v.z);
    o.w = spike_chain(v.w);
    return o;
}

__global__ __launch_bounds__(256) void spike_kernel(const f32x4* __restrict__ x,
                                                    f32x4* __restrict__ out,
                                                    int n4) {
    const int T = gridDim.x * blockDim.x;   // total threads
    int i = blockIdx.x * blockDim.x + threadIdx.x;

    // Exact-cover main path: each thread handles 4 float4 at stride T.
    for (; i + 3 * T < n4; i += 4 * T) {
        f32x4 a = x[i];
        f32x4 b = x[i + T];
        f32x4 c = x[i + 2 * T];
        f32x4 d = x[i + 3 * T];
        f32x4 ra = spike4(a);
        f32x4 rb = spike4(b);
        f32x4 rc = spike4(c);
        f32x4 rd = spike4(d);
        __builtin_nontemporal_store(ra, &out[i]);
        __builtin_nontemporal_store(rb, &out[i + T]);
        __builtin_nontemporal_store(rc, &out[i + 2 * T]);
        __builtin_nontemporal_store(rd, &out[i + 3 * T]);
    }
    // Tail (not taken for the bench shape).
    for (; i < n4; i += T) {
        f32x4 r = spike4(x[i]);
        __builtin_nontemporal_store(r, &out[i]);
    }
}

extern "C" void kernel_launch(void* const* d_in, const int* in_sizes, int n_in,
                              void* d_out, int out_size, void* d_ws, size_t ws_size,
                              hipStream_t stream) {
    const float* x = (const float*)d_in[0];
    float* out = (float*)d_out;
    int n = in_sizes[0];          // 16*4096*1024 = 67,108,864
    int n4 = n >> 2;              // 16,777,216 float4

    const int block = 256;
    // One 4x-float4 chunk per thread: grid = n4 / (4*block) = 16384 blocks.
    int grid = (n4 + 4 * block - 1) / (4 * block);

    spike_kernel<<<grid, block, 0, stream>>>(
        (const f32x4*)x, (f32x4*)out, n4);
}